// Round 1
// baseline (261.913 us; speedup 1.0000x reference)
//
#include <hip/hip_runtime.h>
#include <math.h>

// SparseMaxPool: out2d[b,c,i,j] = max(x[b,c,i..j]) on valid diagonals, else 0.
// valid(d=j-i, i): d in [0,14]  (any i)
//                  d in {16,18,..,30} and i%2==0
//                  d in {34,38,..,62} (d%4==2) and i%4==0
// mask[i][j] = valid(j-i, i)

typedef float f32x4 __attribute__((ext_vector_type(4)));

__device__ __forceinline__ bool valid_ij(int i, int j) {
    const int d = j - i;
    return ((unsigned)d <= 14u)
        || (((i & 1) == 0) && (unsigned)(d - 16) <= 14u && ((d & 1) == 0))
        || (((i & 3) == 0) && (unsigned)(d - 34) <= 28u && ((d & 3) == 2));
}

// Each block: 16 rows. Each wave: 4 rows; 16 lanes per row; each lane owns
// 4 consecutive j (float4 stores). Running max r[s]=max(x[i..4*jq+s]) scanned
// i=63..0; invalid entries zeroed by multiplying with a 0/1 mask float staged
// in LDS. Output stores are nontemporal: 268 MB one-shot stream, zero reuse —
// keep it out of the L2 retention path.
__global__ __launch_bounds__(256) void spmax_kernel(
    const float* __restrict__ x, float* __restrict__ out,
    float* __restrict__ mask_out, int nblocks)
{
    __shared__ __align__(16) float xs[16 * 68];   // 16 rows, +4 pad (bank spread)
    __shared__ __align__(16) float mf[64 * 64];   // 0/1 mask floats, 16 KB

    const int tid = threadIdx.x;

    if ((int)blockIdx.x >= nblocks) {
        // last block: write the 64x64 mask as 0.0/1.0 floats
        #pragma unroll
        for (int k = 0; k < 16; ++k) {
            const int idx = tid + 256 * k;
            __builtin_nontemporal_store(
                valid_ij(idx >> 6, idx & 63) ? 1.0f : 0.0f, mask_out + idx);
        }
        return;
    }

    // stage 16 rows of x: one float4 per thread, coalesced 4 KB
    {
        const float4 v = reinterpret_cast<const float4*>(x)[(size_t)blockIdx.x * 256 + tid];
        const int r = tid >> 4, c4 = tid & 15;
        *reinterpret_cast<float4*>(&xs[r * 68 + 4 * c4]) = v;
    }
    // stage mask floats: 16 entries per thread
    #pragma unroll
    for (int k = 0; k < 16; ++k) {
        const int idx = tid + 256 * k;
        mf[idx] = valid_ij(idx >> 6, idx & 63) ? 1.0f : 0.0f;
    }
    __syncthreads();

    const int lane = tid & 63;
    const int w    = tid >> 6;
    const int rg   = lane >> 4;        // row within wave's group of 4
    const int jq   = lane & 15;        // j quad: owns j = 4*jq .. 4*jq+3
    const int lrow = w * 4 + rg;       // 0..15
    const size_t grow = (size_t)blockIdx.x * 16 + lrow;
    float* obase = out + grow * 4096 + 4 * jq;
    const float* xrow = &xs[lrow * 68];
    const float* mrow = &mf[4 * jq];

    float r0 = -INFINITY, r1 = -INFINITY, r2 = -INFINITY, r3 = -INFINITY;

    #pragma unroll
    for (int g = 15; g >= 0; --g) {
        const float4 X = *reinterpret_cast<const float4*>(&xrow[4 * g]);  // conflict-free
        const float xi4[4] = {X.x, X.y, X.z, X.w};
        #pragma unroll
        for (int s3 = 3; s3 >= 0; --s3) {
            const int i = 4 * g + s3;
            const float v = xi4[s3];
            r0 = fmaxf(r0, v); r1 = fmaxf(r1, v);
            r2 = fmaxf(r2, v); r3 = fmaxf(r3, v);
            // re-init the lane/slot where j == i (kills the i>j garbage phase)
            const bool hit = (jq == (i >> 2));
            switch (i & 3) {                       // compile-time per unrolled i
                case 0: r0 = hit ? v : r0; break;
                case 1: r1 = hit ? v : r1; break;
                case 2: r2 = hit ? v : r2; break;
                case 3: r3 = hit ? v : r3; break;
            }
            const float4 m = *reinterpret_cast<const float4*>(&mrow[i * 64]); // 2-way bcast, free
            f32x4 o;
            o.x = r0 * m.x; o.y = r1 * m.y; o.z = r2 * m.z; o.w = r3 * m.w;
            __builtin_nontemporal_store(
                o, reinterpret_cast<f32x4*>(obase + i * 64));  // 4x256B coalesced, nt
        }
    }
}

extern "C" void kernel_launch(void* const* d_in, const int* in_sizes, int n_in,
                              void* d_out, int out_size, void* d_ws, size_t ws_size,
                              hipStream_t stream) {
    const float* x = (const float*)d_in[0];
    float* out = (float*)d_out;
    const int rows = in_sizes[0] / 64;            // 32*512 = 16384
    const int nblocks = rows / 16;                // 1024
    float* mask_out = out + (out_size - 64 * 64); // mask trails x2d
    spmax_kernel<<<nblocks + 1, 256, 0, stream>>>(x, out, mask_out, nblocks);
}

// Round 2
// 253.600 us; speedup vs baseline: 1.0328x; 1.0328x over previous
//
#include <hip/hip_runtime.h>
#include <math.h>

// SparseMaxPool: out2d[b,c,i,j] = max(x[b,c,i..j]) on valid diagonals, else 0.
// valid(d=j-i, i): d in [0,14]  (any i)
//                  d in {16,18,..,30} and i%2==0
//                  d in {34,38,..,62} (d%4==2) and i%4==0
// mask[i][j] = valid(j-i, i)

typedef float f32x4 __attribute__((ext_vector_type(4)));

__device__ __forceinline__ bool valid_ij(int i, int j) {
    const int d = j - i;
    return ((unsigned)d <= 14u)
        || (((i & 1) == 0) && (unsigned)(d - 16) <= 14u && ((d & 1) == 0))
        || (((i & 3) == 0) && (unsigned)(d - 34) <= 28u && ((d & 3) == 2));
}

// Each block: 16 rows. Each wave: 4 rows; 16 lanes per row; each lane owns
// 4 consecutive j (float4 stores). Running max r[s]=max(x[i..4*jq+s]) scanned
// i=63..0; invalid entries zeroed via 0/1 mask floats staged in LDS.
// Store restructure (this round): output is buffered 8 i-rows at a time in
// registers (statically indexed, fully unrolled) and flushed as ASCENDING
// 2 KB contiguous runs per quarter-wave, instead of 64 descending 256 B
// chunks. Compute order (descending i, verified) is unchanged; only the
// store stream's granularity/direction changes. Probes the DRAM page /
// write-stream-locality theory for the 2x gap vs the fill's 6.4 TB/s.
__global__ __launch_bounds__(256) void spmax_kernel(
    const float* __restrict__ x, float* __restrict__ out,
    float* __restrict__ mask_out, int nblocks)
{
    __shared__ __align__(16) float xs[16 * 68];   // 16 rows, +4 pad (bank spread)
    __shared__ __align__(16) float mf[64 * 64];   // 0/1 mask floats, 16 KB

    const int tid = threadIdx.x;

    if ((int)blockIdx.x >= nblocks) {
        // last block: write the 64x64 mask as 0.0/1.0 floats
        #pragma unroll
        for (int k = 0; k < 16; ++k) {
            const int idx = tid + 256 * k;
            mask_out[idx] = valid_ij(idx >> 6, idx & 63) ? 1.0f : 0.0f;
        }
        return;
    }

    // stage 16 rows of x: one float4 per thread, coalesced 4 KB
    {
        const float4 v = reinterpret_cast<const float4*>(x)[(size_t)blockIdx.x * 256 + tid];
        const int r = tid >> 4, c4 = tid & 15;
        *reinterpret_cast<float4*>(&xs[r * 68 + 4 * c4]) = v;
    }
    // stage mask floats: 16 entries per thread
    #pragma unroll
    for (int k = 0; k < 16; ++k) {
        const int idx = tid + 256 * k;
        mf[idx] = valid_ij(idx >> 6, idx & 63) ? 1.0f : 0.0f;
    }
    __syncthreads();

    const int lane = tid & 63;
    const int w    = tid >> 6;
    const int rg   = lane >> 4;        // row within wave's group of 4
    const int jq   = lane & 15;        // j quad: owns j = 4*jq .. 4*jq+3
    const int lrow = w * 4 + rg;       // 0..15
    const size_t grow = (size_t)blockIdx.x * 16 + lrow;
    float* obase = out + grow * 4096 + 4 * jq;
    const float* xrow = &xs[lrow * 68];
    const float* mrow = &mf[4 * jq];

    float r0 = -INFINITY, r1 = -INFINITY, r2 = -INFINITY, r3 = -INFINITY;

    #pragma unroll
    for (int h = 7; h >= 0; --h) {          // 8 chunks of 8 i's, descending
        f32x4 ob[8];                        // register output buffer (static idx)
        #pragma unroll
        for (int gi = 1; gi >= 0; --gi) {   // two x-quads per chunk, descending
            const int g = 2 * h + gi;
            const float4 X = *reinterpret_cast<const float4*>(&xrow[4 * g]);  // conflict-free
            const float xi4[4] = {X.x, X.y, X.z, X.w};
            #pragma unroll
            for (int s3 = 3; s3 >= 0; --s3) {
                const int i = 4 * g + s3;
                const float v = xi4[s3];
                r0 = fmaxf(r0, v); r1 = fmaxf(r1, v);
                r2 = fmaxf(r2, v); r3 = fmaxf(r3, v);
                // re-init the lane/slot where j == i (kills the i>j garbage phase)
                const bool hit = (jq == (i >> 2));
                switch (i & 3) {                       // compile-time per unrolled i
                    case 0: r0 = hit ? v : r0; break;
                    case 1: r1 = hit ? v : r1; break;
                    case 2: r2 = hit ? v : r2; break;
                    case 3: r3 = hit ? v : r3; break;
                }
                const float4 m = *reinterpret_cast<const float4*>(&mrow[i * 64]); // bcast, free
                f32x4 o;
                o.x = r0 * m.x; o.y = r1 * m.y; o.z = r2 * m.z; o.w = r3 * m.w;
                ob[4 * gi + s3] = o;
            }
        }
        // flush chunk as an ascending 2 KB contiguous run per quarter-wave
        #pragma unroll
        for (int k = 0; k < 8; ++k) {
            *reinterpret_cast<f32x4*>(obase + (8 * h + k) * 64) = ob[k];
        }
    }
}

extern "C" void kernel_launch(void* const* d_in, const int* in_sizes, int n_in,
                              void* d_out, int out_size, void* d_ws, size_t ws_size,
                              hipStream_t stream) {
    const float* x = (const float*)d_in[0];
    float* out = (float*)d_out;
    const int rows = in_sizes[0] / 64;            // 32*512 = 16384
    const int nblocks = rows / 16;                // 1024
    float* mask_out = out + (out_size - 64 * 64); // mask trails x2d
    spmax_kernel<<<nblocks + 1, 256, 0, stream>>>(x, out, mask_out, nblocks);
}